// Round 5
// baseline (116.012 us; speedup 1.0000x reference)
//
#include <hip/hip_runtime.h>
#include <stdint.h>
#include <float.h>

#define BLK 256
#define IPT 8                 // owner points per thread (8 independent min-chains)
#define OWNERS (BLK * IPT)    // 2048 owners per block
#define SLICE 128             // scanned points per block (2 KB LDS)
#define SUB 64                // subtile granularity for deferred-index recovery

typedef unsigned long long ull;

// Monotone float -> uint transform (preserves <, total order) and inverse.
__device__ __forceinline__ unsigned int ford(float f) {
    int b = __float_as_int(f);
    return (b >= 0) ? ((unsigned)b ^ 0x80000000u) : ~(unsigned)b;
}
__device__ __forceinline__ float ford_inv(unsigned int u) {
    int b = (u & 0x80000000u) ? (int)(u ^ 0x80000000u) : (int)~u;
    return __int_as_float(b);
}

// Guaranteed single v_min_f32 (fminf can grow NaN-canonicalization ops in IEEE
// mode; inputs here are always finite so semantics are identical).
__device__ __forceinline__ float vmin(float a, float b) {
    float d;
    asm("v_min_f32 %0, %1, %2" : "=v"(d) : "v"(a), "v"(b));
    return d;
}

// Phase 1: min VALUE only (3 v_fma + 1 v_min per pair). Per 64-point subtile,
// record the subtile base if the running min improved (strict <: first-improving
// subtile wins). Merge via u64 atomicMin of (ford(best)<<32 | subtile_base):
// equal values resolve to the smallest base = numpy first occurrence. Exact
// index recovered in finalize by bit-identical re-scan of the 64-pt subtile.
__global__ __launch_bounds__(BLK) void nn_min_dual(
    const float* __restrict__ p, const float* __restrict__ g,
    ull* __restrict__ rowmin, ull* __restrict__ colmin,
    int rowBlocks, int rowSlices, int colSlices)
{
    __shared__ float4 sb[SLICE];

    const float* A; const float* B; ull* outmin; int id, nSlices;
    if ((int)blockIdx.x < rowBlocks) {
        id = blockIdx.x;             A = p; B = g; outmin = rowmin; nSlices = rowSlices;
    } else {
        id = blockIdx.x - rowBlocks; A = g; B = p; outmin = colmin; nSlices = colSlices;
    }
    const int chunk = id / nSlices;
    const int slice = id - chunk * nSlices;
    const int s0 = slice * SLICE;

    // Stage slice (coords + |B|^2). Explicit fmaf: finalize recomputes the
    // identical expression so bit-exact equality holds.
    if (threadIdx.x < SLICE) {
        int s = s0 + threadIdx.x;
        float bx = B[3 * s], by = B[3 * s + 1], bz = B[3 * s + 2];
        float w = fmaf(bz, bz, fmaf(by, by, bx * bx));
        sb[threadIdx.x] = make_float4(bx, by, bz, w);
    }

    const int o0 = chunk * OWNERS + threadIdx.x;
    float ax[IPT], ay[IPT], az[IPT], best[IPT];
    int base[IPT];
#pragma unroll
    for (int r = 0; r < IPT; ++r) {
        int o = o0 + r * BLK;
        ax[r] = -2.0f * A[3 * o];
        ay[r] = -2.0f * A[3 * o + 1];
        az[r] = -2.0f * A[3 * o + 2];
        best[r] = FLT_MAX;
        base[r] = s0;
    }
    __syncthreads();

    for (int st = 0; st < SLICE; st += SUB) {
        float prev[IPT];
#pragma unroll
        for (int r = 0; r < IPT; ++r) prev[r] = best[r];
#pragma unroll 4
        for (int k = st; k < st + SUB; ++k) {
            float4 q = sb[k];    // wave-uniform broadcast read
#pragma unroll
            for (int r = 0; r < IPT; ++r) {
                float v = fmaf(ax[r], q.x, fmaf(ay[r], q.y, fmaf(az[r], q.z, q.w)));
                best[r] = vmin(best[r], v);
            }
        }
#pragma unroll
        for (int r = 0; r < IPT; ++r)
            if (best[r] < prev[r]) base[r] = s0 + st;   // strict <: first subtile wins
    }

#pragma unroll
    for (int r = 0; r < IPT; ++r) {
        ull packed = ((ull)ford(best[r]) << 32) | (unsigned)base[r];
        atomicMin(&outmin[o0 + r * BLK], packed);
    }
}

// Phase 2 + finalize: per owner, branchless re-scan of the winning 64-pt
// subtile with the exact same fma chain; first index attaining the min via
// integer-min (no early exit -> loads pipeline). Then gather normal and
// accumulate mean(1 - dot) for both directions.
__global__ __launch_bounds__(BLK) void finalize_kernel(
    const ull* __restrict__ rowmin, const ull* __restrict__ colmin,
    const float* __restrict__ p, const float* __restrict__ g,
    const float* __restrict__ pn, const float* __restrict__ gn,
    float* __restrict__ out, int N, int M, float invN, float invM)
{
    int t = blockIdx.x * BLK + threadIdx.x;
    float c = 0.0f;
    if (t < N + M) {
        const float* A; const float* B; const float* An; const float* Bn;
        ull packed; int o; float inv;
        if (t < N) { o = t;     A = p; B = g; An = pn; Bn = gn; packed = rowmin[o]; inv = invN; }
        else       { o = t - N; A = g; B = p; An = gn; Bn = pn; packed = colmin[o]; inv = invM; }

        float ax = -2.0f * A[3 * o];
        float ay = -2.0f * A[3 * o + 1];
        float az = -2.0f * A[3 * o + 2];
        float bestf = ford_inv((unsigned int)(packed >> 32));
        int base = (int)(packed & 0xffffffffull);

        int idx = 0x7fffffff;
#pragma unroll 8
        for (int j = 0; j < SUB; ++j) {
            int s = base + j;
            float bx = B[3 * s], by = B[3 * s + 1], bz = B[3 * s + 2];
            float w = fmaf(bz, bz, fmaf(by, by, bx * bx));
            float v = fmaf(ax, bx, fmaf(ay, by, fmaf(az, bz, w)));
            idx = min(idx, (v == bestf) ? s : 0x7fffffff);  // first bit-exact match
        }

        float d = An[3 * o] * Bn[3 * idx] + An[3 * o + 1] * Bn[3 * idx + 1]
                + An[3 * o + 2] * Bn[3 * idx + 2];
        c = (1.0f - d) * inv;
    }
#pragma unroll
    for (int off = 32; off > 0; off >>= 1) c += __shfl_down(c, off, 64);
    __shared__ float partial[BLK / 64];
    if ((threadIdx.x & 63) == 0) partial[threadIdx.x >> 6] = c;
    __syncthreads();
    if (threadIdx.x == 0) {
        float s = 0.0f;
#pragma unroll
        for (int w = 0; w < BLK / 64; ++w) s += partial[w];
        atomicAdd(out, s);
    }
}

extern "C" void kernel_launch(void* const* d_in, const int* in_sizes, int n_in,
                              void* d_out, int out_size, void* d_ws, size_t ws_size,
                              hipStream_t stream) {
    const float* p  = (const float*)d_in[0];   // [N,3] predicted points
    const float* pn = (const float*)d_in[1];   // [N,3] predicted normals (unit)
    const float* g  = (const float*)d_in[2];   // [M,3] gt points
    const float* gn = (const float*)d_in[3];   // [M,3] gt normals (unit)
    const int N = in_sizes[0] / 3;             // 8192
    const int M = in_sizes[2] / 3;             // 32768

    ull* rowmin = (ull*)d_ws;                  // [N]
    ull* colmin = rowmin + N;                  // [M]
    float* out = (float*)d_out;

    hipMemsetAsync(d_ws, 0xFF, (size_t)(N + M) * sizeof(ull), stream);
    hipMemsetAsync(d_out, 0, sizeof(float), stream);

    const int rowSlices = M / SLICE;                 // 256
    const int colSlices = N / SLICE;                 // 64
    const int rowBlocks = (N / OWNERS) * rowSlices;  // 4*256  = 1024
    const int colBlocks = (M / OWNERS) * colSlices;  // 16*64  = 1024
    nn_min_dual<<<rowBlocks + colBlocks, BLK, 0, stream>>>(
        p, g, rowmin, colmin, rowBlocks, rowSlices, colSlices);

    int tot = N + M;
    finalize_kernel<<<(tot + BLK - 1) / BLK, BLK, 0, stream>>>(
        rowmin, colmin, p, g, pn, gn, out, N, M, 1.0f / N, 1.0f / M);
}